// Round 1
// baseline (452.193 us; speedup 1.0000x reference)
//
#include <hip/hip_runtime.h>
#include <hip/hip_bf16.h>
#include <cstdint>

typedef __attribute__((ext_vector_type(4))) float f32x4;
typedef __attribute__((ext_vector_type(4))) int i32x4;

#define IN_F 4096
#define OUT_F 4096
#define N_TOK 8192
#define NUM_FREQ 16

// ---------- helpers ----------

__device__ inline float fast_tanh(float x) {
    float ax = fabsf(x);
    float e = __expf(2.0f * ax);
    float t = 1.0f - 2.0f / (e + 1.0f);
    return copysignf(t, x);
}

__device__ inline void load_lds16(const void* g, void* l) {
    __builtin_amdgcn_global_load_lds(
        (const __attribute__((address_space(1))) void*)(uintptr_t)g,
        (__attribute__((address_space(3))) void*)(uint32_t)(uintptr_t)l,
        16, 0, 0);
}

__device__ inline int q8(float v, float s) {
    int q = (int)rintf(v * s);
    return min(127, max(-127, q));
}

__device__ inline unsigned int pack4(int q0, int q1, int q2, int q3) {
    return (q0 & 255) | ((q1 & 255) << 8) | ((q2 & 255) << 16) |
           ((q3 & 255) << 24);
}

// ---------- kernel 1: fused W synthesis->i8 + x quantize->i8 ----------
// blocks [0, OUT_F)               : synth W row o, per-row absmax, quantize
// blocks [OUT_F, OUT_F + N_TOK)   : quantize x row t, per-row absmax
__global__ __launch_bounds__(256)
void prep(const float* __restrict__ x, signed char* __restrict__ xq,
          float* __restrict__ sx, const float* __restrict__ amp,
          const float* __restrict__ rf, const float* __restrict__ cf,
          const float* __restrict__ rp, const float* __restrict__ cp,
          const float* __restrict__ lA, const float* __restrict__ lB,
          const float* __restrict__ alpha, const float* __restrict__ beta,
          signed char* __restrict__ wq, float* __restrict__ sw) {
    const int tid = threadIdx.x;
    const int wave = tid >> 6;
    const int lane = tid & 63;
    __shared__ float s_s[NUM_FREQ], s_cf[NUM_FREQ], s_cp[NUM_FREQ];
    __shared__ float red[4];

    if (blockIdx.x < OUT_F) {
        // ---- W synthesis + quantize ----
        const int o = blockIdx.x;
        const float step = 6.28318530717958647692f / 4095.0f;
        if (tid < NUM_FREQ) {
            float r = step * (float)o;
            s_s[tid] = amp[tid] * __sinf(r * rf[tid] + rp[tid]);
            s_cf[tid] = cf[tid];
            s_cp[tid] = cp[tid];
        }
        __syncthreads();
        const float sa = 1.0f / (1.0f + __expf(-alpha[0]));
        const float sb = 1.0f / (1.0f + __expf(-beta[0]));
        const float stdv = 0.015625f;  // sqrt(2/8192) = 1/64 exactly
        const float a0 = lA[o * 2 + 0];
        const float a1 = lA[o * 2 + 1];

        float w[16];
        const int ibase = tid * 16;
        const f32x4* lB4 = (const f32x4*)lB;
#pragma unroll
        for (int g = 0; g < 4; ++g) {
            f32x4 b0 = lB4[tid * 4 + g];
            f32x4 b1 = lB4[1024 + tid * 4 + g];
#pragma unroll
            for (int e = 0; e < 4; ++e) {
                int j = g * 4 + e;
                float ci = step * (float)(ibase + j);
                float wf = 0.0f;
#pragma unroll
                for (int k = 0; k < NUM_FREQ; ++k)
                    wf += s_s[k] * __cosf(ci * s_cf[k] + s_cp[k]);
                float wl = a0 * b0[e] + a1 * b1[e];
                w[j] = sa * stdv * fast_tanh(wf) + sb * stdv * fast_tanh(wl);
            }
        }
        // block absmax reduction
        float m = 0.0f;
#pragma unroll
        for (int j = 0; j < 16; ++j) m = fmaxf(m, fabsf(w[j]));
#pragma unroll
        for (int off = 32; off > 0; off >>= 1)
            m = fmaxf(m, __shfl_xor(m, off));
        if (lane == 0) red[wave] = m;
        __syncthreads();
        m = fmaxf(fmaxf(red[0], red[1]), fmaxf(red[2], red[3]));
        m = fmaxf(m, 1e-20f);
        const float s = 127.0f / m;
        uint4 out;
        unsigned int* op = (unsigned int*)&out;
#pragma unroll
        for (int g = 0; g < 4; ++g)
            op[g] = pack4(q8(w[g * 4], s), q8(w[g * 4 + 1], s),
                          q8(w[g * 4 + 2], s), q8(w[g * 4 + 3], s));
        *(uint4*)(wq + (size_t)o * IN_F + ibase) = out;
        if (tid == 0) sw[o] = m / 127.0f;
    } else {
        // ---- x quantize ----
        const int t = blockIdx.x - OUT_F;
        const f32x4* xr = (const f32x4*)(x + (size_t)t * IN_F);
        f32x4 v[4];
#pragma unroll
        for (int j = 0; j < 4; ++j) v[j] = xr[tid + 256 * j];
        float m = 0.0f;
#pragma unroll
        for (int j = 0; j < 4; ++j)
#pragma unroll
            for (int e = 0; e < 4; ++e) m = fmaxf(m, fabsf(v[j][e]));
#pragma unroll
        for (int off = 32; off > 0; off >>= 1)
            m = fmaxf(m, __shfl_xor(m, off));
        if (lane == 0) red[wave] = m;
        __syncthreads();
        m = fmaxf(fmaxf(red[0], red[1]), fmaxf(red[2], red[3]));
        m = fmaxf(m, 1e-20f);
        const float s = 127.0f / m;
        unsigned int* orow = (unsigned int*)(xq + (size_t)t * IN_F);
#pragma unroll
        for (int j = 0; j < 4; ++j)
            orow[tid + 256 * j] =
                pack4(q8(v[j][0], s), q8(v[j][1], s), q8(v[j][2], s),
                      q8(v[j][3], s));
        if (tid == 0) sx[t] = m / 127.0f;
    }
}

// ---------- kernel 2: i8 MFMA GEMM, C = (sx.sw^T) * (Aq @ Bq^T) + bias ----
// Round-4 changes (theory: LDS-read-throughput bound, 68% LDS busy incl.
// 27us/CU of bank conflicts vs 70us MFMA floor):
//  1. XOR bank swizzle: element (row, 16B-unit u) of each 64B LDS row is
//     stored at unit u ^ ((row>>1)&3). global_load_lds writes LINEARLY
//     (wave-uniform base + lane*16), so the swizzle is applied by
//     pre-swizzling the GLOBAL source column per lane (rule: both-sides-
//     or-neither). A full-wave ds_read_b128 then hits every bank exactly
//     8x4B -> conflict-free (was: 8 of 32 banks per quarter-wave).
//  2. Wave tile 64x64 -> 128x64 (8x4 frags): reads/iter per wave 16->24
//     for MFMAs 32->64, i.e. LDS bytes per MFMA-op cut 1.36x. BM=256,
//     BN=128, acc=128 VGPRs (was 64 total -> headroom exists).
// Predicted: SQ_LDS_BANK_CONFLICT 1.7e7 -> <2e6, MfmaUtil 38 -> ~55-65,
// gemm 161us -> ~95-110us.
#define BM 256
#define BN 128
#define BKB 128
#define SUBK 64

__global__ __launch_bounds__(256, 2)
void gemm_i8(const signed char* __restrict__ A, const signed char* __restrict__ B,
             const float* __restrict__ sx, const float* __restrict__ sw,
             const float* __restrict__ bias, float* __restrict__ C,
             int M, int N, int K) {
    __shared__ signed char sA[2][BM * SUBK];  // 2 x 16 KB
    __shared__ signed char sB[2][BN * SUBK];  // 2 x 8 KB

    const int tid = threadIdx.x;
    const int wave = tid >> 6;
    const int lane = tid & 63;

    const int bm = blockIdx.y * BM;
    const int bn = blockIdx.x * BN;

    // staging: one call = 16 rows x 64B (1KB, linear in LDS).
    // lane l -> row = l>>2 (within chunk), slot s = l&3.
    // source column unit = s ^ ((row>>1)&3) = s ^ ((l>>3)&3)  [swizzle]
    const int srow = lane >> 2;
    const int scol = (((lane & 3) ^ ((lane >> 3) & 3)) << 4);

    const signed char* gA = A + (size_t)(bm + wave * 16 + srow) * K + scol;
    const signed char* gB = B + (size_t)(bn + wave * 16 + srow) * K + scol;

    // reads: row = (wtile + i*16 + lm), 16B unit = quad ^ ((row>>1)&3);
    // (row>>1)&3 == (lm>>1)&3 because all other row terms are mult of 16.
    const int lm = lane & 15;
    const int quad = lane >> 4;
    const int kq = ((quad ^ ((lm >> 1) & 3)) << 4);

    const int wm = (wave & 1) * 128;  // wave M offset in tile
    const int wn = (wave >> 1) * 64;  // wave N offset in tile
    const int aoff = (wm + lm) * SUBK + kq;
    const int boff = (wn + lm) * SUBK + kq;

    i32x4 acc[8][4] = {};

    for (int k0 = 0; k0 < K; k0 += BKB) {
#pragma unroll
        for (int h = 0; h < 2; ++h) {
            const int kk = k0 + h * SUBK;
#pragma unroll
            for (int c = 0; c < 4; ++c)
                load_lds16(gA + (size_t)c * 64 * K + kk,
                           &sA[h][(wave * 16 + c * 64) * SUBK]);
#pragma unroll
            for (int c = 0; c < 2; ++c)
                load_lds16(gB + (size_t)c * 64 * K + kk,
                           &sB[h][(wave * 16 + c * 64) * SUBK]);
        }
        __syncthreads();

#pragma unroll
        for (int h = 0; h < 2; ++h) {
            i32x4 af[8], bv[4];
#pragma unroll
            for (int i = 0; i < 8; ++i)
                af[i] = *(const i32x4*)&sA[h][aoff + i * 16 * SUBK];
#pragma unroll
            for (int i = 0; i < 4; ++i)
                bv[i] = *(const i32x4*)&sB[h][boff + i * 16 * SUBK];

#pragma unroll
            for (int im = 0; im < 8; ++im)
#pragma unroll
                for (int in = 0; in < 4; ++in)
                    acc[im][in] = __builtin_amdgcn_mfma_i32_16x16x64_i8(
                        af[im], bv[in], acc[im][in], 0, 0, 0);
        }

        __syncthreads();
    }

    // epilogue: D layout col = lane&15, row = quad*4 + r
    float sxv[8][4];
#pragma unroll
    for (int im = 0; im < 8; ++im)
#pragma unroll
        for (int r = 0; r < 4; ++r)
            sxv[im][r] = sx[bm + wm + im * 16 + quad * 4 + r];

#pragma unroll
    for (int in = 0; in < 4; ++in) {
        const int cn = bn + wn + in * 16 + lm;
        const float bv_ = bias[cn];
        const float scw = sw[cn];
#pragma unroll
        for (int im = 0; im < 8; ++im) {
            const int rm = bm + wm + im * 16 + quad * 4;
#pragma unroll
            for (int r = 0; r < 4; ++r)
                C[(size_t)(rm + r) * N + cn] =
                    (float)acc[im][in][r] * (sxv[im][r] * scw) + bv_;
        }
    }
}

// ---------- launch ----------
extern "C" void kernel_launch(void* const* d_in, const int* in_sizes, int n_in,
                              void* d_out, int out_size, void* d_ws,
                              size_t ws_size, hipStream_t stream) {
    const float* x = (const float*)d_in[0];
    const float* amp = (const float*)d_in[1];
    const float* rf = (const float*)d_in[2];
    const float* cf = (const float*)d_in[3];
    const float* rp = (const float*)d_in[4];
    const float* cp = (const float*)d_in[5];
    const float* lA = (const float*)d_in[6];
    const float* lB = (const float*)d_in[7];
    const float* alpha = (const float*)d_in[8];
    const float* beta = (const float*)d_in[9];
    const float* bias = (const float*)d_in[10];
    float* out = (float*)d_out;

    signed char* wq = (signed char*)d_ws;                       // 16 MiB
    signed char* xq = wq + (size_t)OUT_F * IN_F;                // 32 MiB
    float* sw = (float*)(xq + (size_t)N_TOK * IN_F);            // 16 KiB
    float* sx = sw + OUT_F;                                     // 32 KiB

    prep<<<OUT_F + N_TOK, 256, 0, stream>>>(x, xq, sx, amp, rf, cf, rp, cp,
                                            lA, lB, alpha, beta, wq, sw);
    gemm_i8<<<dim3(OUT_F / BN, N_TOK / BM), 256, 0, stream>>>(
        xq, wq, sx, sw, bias, out, N_TOK, OUT_F, IN_F);
}